// Round 8
// baseline (2705.605 us; speedup 1.0000x reference)
//
#include <hip/hip_runtime.h>
#include <stdint.h>

// Problem constants
#define B_   64
#define T_   512
#define E_   256
#define H_   512
#define G4_  2048   // 4*H
#define V_   32000

// Output layout in d_out (floats): seq [64][512][512], h_last [64][512], mask [64][512]
#define OUT_SEQ   0
#define OUT_HLAST 16777216
#define OUT_MASK  16809984

// ws layout (bytes)
#define OFF_EMB  0u            // emb bf16 [32000][256]  = 16,384,000
#define OFF_WXT  16384000u     // WxT bf16 [2048][256]   =  1,048,576
#define OFF_WHT  17432576u     // WhT bf16 [2048][512]   =  2,097,152
#define OFF_C    19529728u     // cbuf f32  [64][512]    =    131,072
#define OFF_FLAG 19660800u     // flags u32 [4 groups][32 waves] = 512 B (+pad)
#define OFF_XZ   19664896u     // xz bf16 [TC][64][2048] = TC*262,144, then h-ring
#define XZ_PER_T   262144u
#define RING_PER_T  65536u     // one h slot: 4 groups x 64 kc x 16 b x 8 cols bf16
#define SLOT_U64    8192       // 65536 / 8

// h-slot layout (u64 units): idx = ((g*64 + kc)*16 + b)*2 + half
//   g = batch group (b/16), kc = j/8, b = batch within group, half = (j/4)&1.
// Consumer wave (lane l15=row, l4=k-quarter) reads, per ks, u64 pair at
//   (g*64 + ks*4 + l4)*32 + l15*2  -> lanes cover 1KB contiguous per instr.
//
// Sync protocol (R8): per-wave MONOTONIC flag. Producer wave: h stores
// (relaxed agent u64) -> s_waitcnt vmcnt(0) (acks at coherence point) ->
// flag[g*32 + wv] = t+1 (relaxed store, no RMW). Consumer at step t spins on
// the 128B flag line (>= t for all 32 group waves), then reads the 16KB h
// tile ONCE, unconditionally. No poison, no data re-reads, no fences.

typedef short bf16x8 __attribute__((ext_vector_type(8)));
typedef float f32x4  __attribute__((ext_vector_type(4)));
typedef unsigned int u32x4 __attribute__((ext_vector_type(4)));

__device__ __forceinline__ unsigned short f2bf(float f) {
  uint32_t u = __float_as_uint(f);
  u = (u + 0x7FFFu + ((u >> 16) & 1u)) >> 16;   // RNE
  return (unsigned short)u;
}
__device__ __forceinline__ float bf2f(unsigned short h) {
  return __uint_as_float(((uint32_t)h) << 16);
}
// inf-safe fast gates
__device__ __forceinline__ float sigmoid_f(float x) {
  return __fdividef(1.f, 1.f + __expf(-x));
}
__device__ __forceinline__ float tanh_f(float x) {
  return 1.f - __fdividef(2.f, 1.f + __expf(2.f * x));
}

// ---------- prep: cast embedding table to bf16 ----------
__global__ void k_prep_emb(const float* __restrict__ emb, unsigned short* __restrict__ out) {
  int i = (blockIdx.x * 256 + threadIdx.x) * 4;   // 8,192,000 elems total
  if (i < V_ * E_) {
    float4 v = *(const float4*)(emb + i);
    ushort4 o;
    o.x = f2bf(v.x); o.y = f2bf(v.y); o.z = f2bf(v.z); o.w = f2bf(v.w);
    *(ushort4*)(out + i) = o;
  }
}

// ---------- prep: WxT, WhT (transposed bf16 copies) ----------
__global__ void k_prep_w(const float* __restrict__ Wx, const float* __restrict__ Wh,
                         unsigned short* __restrict__ wxt, unsigned short* __restrict__ wht) {
  int i = blockIdx.x * 256 + threadIdx.x;
  if (i < 524288) {                       // WxT[n][k] = Wx[k][n]
    int n = i >> 8, k = i & 255;
    wxt[i] = f2bf(Wx[k * G4_ + n]);
  } else if (i < 524288 + 1048576) {      // WhT[n][k] = Wh[k][n]
    int j = i - 524288;
    int n = j >> 9, k = j & 511;
    wht[j] = f2bf(Wh[k * G4_ + n]);
  }
}

// ---------- mask output ----------
__global__ void k_mask(const int* __restrict__ seq, float* __restrict__ out) {
  int i = blockIdx.x * 256 + threadIdx.x;       // 32768
  if (i < B_ * T_) out[OUT_MASK + i] = (seq[i] != 0) ? 1.f : 0.f;
}

// ---------- outseq: ring slot [g][kc][b][8] bf16 -> out [b][t][j] f32 ----------
__global__ __launch_bounds__(256) void k_copyseq(const unsigned int* __restrict__ ring,
                                                 float* __restrict__ out, int t0, int R) {
  int t = t0 + blockIdx.x;
  const unsigned int* src = ring + (size_t)(t % R) * (SLOT_U64 * 2);
  for (int i = threadIdx.x; i < B_ * H_ / 2; i += 256) {
    int b = i >> 8;
    int j = (i & 255) * 2;
    unsigned int v = src[((((b >> 4) * 64 + (j >> 3)) * 16 + (b & 15)) * 4) + ((j >> 1) & 3)];
    float2 o;
    o.x = bf2f((unsigned short)(v & 0xFFFFu));
    o.y = bf2f((unsigned short)(v >> 16));
    *(float2*)(out + ((size_t)b * T_ + t) * H_ + j) = o;
  }
}

// ---------- h_last from ring slot (T-1)%R ----------
__global__ void k_hlast(const unsigned int* __restrict__ ring, float* __restrict__ out, int R) {
  int i = blockIdx.x * 256 + threadIdx.x;       // 32768
  if (i < B_ * H_) {
    int b = i >> 9, j = i & 511;
    unsigned int v = ring[(size_t)((T_ - 1) % R) * (SLOT_U64 * 2) +
                          ((((b >> 4) * 64 + (j >> 3)) * 16 + (b & 15)) * 4) + ((j >> 1) & 3)];
    out[OUT_HLAST + i] = bf2f((unsigned short)((j & 1) ? (v >> 16) : (v & 0xFFFFu)));
  }
}

// ---------- phase 1: xz[m][n] = emb[seq][.]@Wx + b, m = (t-t0)*64 + b, bf16 out ----------
#define LDA_ 264
__global__ __launch_bounds__(256) void k_gemm_xz(
    const int* __restrict__ seq, const unsigned short* __restrict__ embb,
    const unsigned short* __restrict__ wxt, const float* __restrict__ bias,
    unsigned short* __restrict__ xz, int t0) {
  __shared__ __align__(16) unsigned short a_lds[128 * LDA_];
  __shared__ __align__(16) unsigned short b_lds[128 * LDA_];
  int bx = blockIdx.x & 15;     // N tile
  int by = blockIdx.x >> 4;     // M tile (chunk-local)
  int tid = threadIdx.x;

  { // stage A (gathered embedding rows) and B (WxT rows): 2 threads per 512B row
    int r = tid >> 1, half = tid & 1;
    int m = by * 128 + r;
    int t = t0 + (m >> 6), b = m & 63;
    int idx = seq[b * T_ + t];
    const unsigned short* srcA = embb + (size_t)idx * E_ + half * 128;
    const unsigned short* srcB = wxt + (size_t)(bx * 128 + r) * E_ + half * 128;
    unsigned short* dstA = a_lds + r * LDA_ + half * 128;
    unsigned short* dstB = b_lds + r * LDA_ + half * 128;
#pragma unroll
    for (int q = 0; q < 16; ++q) {
      *(bf16x8*)(dstA + q * 8) = *(const bf16x8*)(srcA + q * 8);
      *(bf16x8*)(dstB + q * 8) = *(const bf16x8*)(srcB + q * 8);
    }
  }
  __syncthreads();

  int w = tid >> 6, lane = tid & 63;
  int l15 = lane & 15, l4 = lane >> 4;
  int wm = w >> 1, wn = w & 1;
  f32x4 acc[4][4] = {};
#pragma unroll
  for (int ks = 0; ks < 8; ++ks) {
    bf16x8 a[4], bb[4];
#pragma unroll
    for (int mf = 0; mf < 4; ++mf)
      a[mf] = *(const bf16x8*)(a_lds + (wm * 64 + mf * 16 + l15) * LDA_ + ks * 32 + 8 * l4);
#pragma unroll
    for (int nf = 0; nf < 4; ++nf)
      bb[nf] = *(const bf16x8*)(b_lds + (wn * 64 + nf * 16 + l15) * LDA_ + ks * 32 + 8 * l4);
#pragma unroll
    for (int mf = 0; mf < 4; ++mf)
#pragma unroll
      for (int nf = 0; nf < 4; ++nf)
        acc[mf][nf] = __builtin_amdgcn_mfma_f32_16x16x32_bf16(a[mf], bb[nf], acc[mf][nf], 0, 0, 0);
  }
#pragma unroll
  for (int nf = 0; nf < 4; ++nf) {
    int n = bx * 128 + wn * 64 + nf * 16 + l15;
    float bv = bias[n];
#pragma unroll
    for (int mf = 0; mf < 4; ++mf)
#pragma unroll
      for (int q = 0; q < 4; ++q) {
        int m = by * 128 + wm * 64 + mf * 16 + l4 * 4 + q;
        xz[(size_t)m * G4_ + n] = f2bf(acc[mf][nf][q] + bv);
      }
  }
}

// ---------- phase 2: persistent LSTM recurrence (R5 geometry + flag protocol) ----------
// 64 WGs x 128 thr (2 waves): group g = bid&3 (16 batches), WG owns j-slice
// [32*(bid>>2), +32); wave w covers 16 j-cols x 4 gates; Wh frags pinned in
// registers via identity asm.
__global__ __launch_bounds__(128, 1) void k_lstm(
    const unsigned short* __restrict__ wht, const unsigned short* __restrict__ xz,
    unsigned long long* hring, float* cbuf, unsigned int* flags,
    int t0, int tend, int R) {
  int bid = blockIdx.x;
  int g = bid & 3, nwg = bid >> 2;        // nwg in 0..15
  int J0 = nwg * 32;
  int tid = threadIdx.x;
  int w = tid >> 6, lane = tid & 63;
  int l15 = lane & 15, l4 = lane >> 4;
  int bglob0 = g * 16;
  int jcol = J0 + w * 16 + l15;          // this lane's j column (per gate)

  // B fragments in registers, pinned: Bs[gt][ks] = WhT[gt*512+jcol][ks*32+l4*8..+7]
  u32x4 Bs[4][16];
#pragma unroll
  for (int gt = 0; gt < 4; ++gt)
#pragma unroll
    for (int ks = 0; ks < 16; ++ks) {
      Bs[gt][ks] = *(const u32x4*)(wht + (size_t)(gt * 512 + jcol) * H_ + ks * 32 + l4 * 8);
      asm volatile("" : "+v"(Bs[gt][ks]));
    }

  float c4[4];
  if (t0 == 0) {
    c4[0] = c4[1] = c4[2] = c4[3] = 0.f;
  } else {
#pragma unroll
    for (int q = 0; q < 4; ++q) c4[q] = cbuf[(bglob0 + l4 * 4 + q) * H_ + jcol];
  }

  // producer store slot-cell base (u64): ((g*64 + jcol/8)*16)*2 + (jcol/4)&1, + b*2 per q
  size_t pbase = ((size_t)(g * 64 + (jcol >> 3)) * 16) * 2 + ((jcol >> 2) & 1);
  // consumer read base (u64): (g*64 + ks*4 + l4)*32 + l15*2, ks stride 128
  size_t rbase = (size_t)(g * 64 + l4) * 32 + l15 * 2;
  unsigned int* myflag = flags + (g * 32 + nwg * 2 + w);
  const unsigned int* gflags = flags + g * 32;

  int xoff[16];
#pragma unroll
  for (int gt = 0; gt < 4; ++gt)
#pragma unroll
    for (int q = 0; q < 4; ++q)
      xoff[gt * 4 + q] = (l4 * 4 + q) * G4_ + gt * 512 + jcol;

  // xzf holds this step's input projections as f32
  float xzf[16];
  {
    const unsigned short* x0 = xz + (size_t)bglob0 * G4_;   // chunk-local t index 0
#pragma unroll
    for (int k = 0; k < 16; ++k) xzf[k] = bf2f(x0[xoff[k]]);
  }

  int t = t0;
  if (t0 == 0) {
    // step 0: h = gates(xz), c from zero
    unsigned long long* hdst = hring;           // slot 0
#pragma unroll
    for (int q = 0; q < 4; ++q) {
      float ig = sigmoid_f(xzf[0 * 4 + q]);
      float gg = tanh_f(xzf[2 * 4 + q]);
      float og = sigmoid_f(xzf[3 * 4 + q]);
      float cn = ig * gg;                       // f*c0 = 0
      c4[q] = cn;
      float hv = og * tanh_f(cn);
      unsigned int my = f2bf(hv);
      unsigned int p1 = __shfl_xor(my, 1);
      unsigned int pair = my | (p1 << 16);
      unsigned int hi2 = __shfl_xor(pair, 2);
      if ((l15 & 3) == 0) {
        unsigned long long vv = (unsigned long long)pair | ((unsigned long long)hi2 << 32);
        __hip_atomic_store(&hdst[pbase + (size_t)(l4 * 4 + q) * 2], vv,
                           __ATOMIC_RELAXED, __HIP_MEMORY_SCOPE_AGENT);
      }
    }
    asm volatile("s_waitcnt vmcnt(0)" ::: "memory");   // h stores at coherence point
    if (lane == 0)
      __hip_atomic_store(myflag, 1u, __ATOMIC_RELAXED, __HIP_MEMORY_SCOPE_AGENT);
    t = 1;
    if (t < tend) {
      const unsigned short* x1 = xz + ((size_t)1 * B_ + bglob0) * G4_;
#pragma unroll
      for (int k = 0; k < 16; ++k) xzf[k] = bf2f(x1[xoff[k]]);
    }
  }

  for (; t < tend; ++t) {
    // prefetch next step's xz (overlaps the flag wait)
    unsigned int raw[16];
    const unsigned short* xn = xz + ((size_t)(t + 1 - t0) * B_ + bglob0) * G4_;
    if (t + 1 < tend) {
#pragma unroll
      for (int k = 0; k < 16; ++k) raw[k] = xn[xoff[k]];
    }
    __builtin_amdgcn_sched_barrier(0);

    // flag spin: 64B/wave/round -- wait until all 32 group waves report >= t
    {
      unsigned int need = (unsigned int)t;
      while (true) {
        unsigned int fv = __hip_atomic_load(gflags + (lane & 31),
                                            __ATOMIC_RELAXED, __HIP_MEMORY_SCOPE_AGENT);
        if (__all(fv >= need)) break;
      }
    }
    asm volatile("" ::: "memory");
    __builtin_amdgcn_sched_barrier(0);

    // one-shot h_{t-1} read: 32 coalesced u64 loads, no validation needed
    const unsigned long long* hsrc = hring + (size_t)((t - 1) % R) * SLOT_U64 + rbase;
    unsigned long long v[32];
#pragma unroll
    for (int ks = 0; ks < 16; ++ks) {
      v[2 * ks]     = __hip_atomic_load(hsrc + (size_t)ks * 128,     __ATOMIC_RELAXED, __HIP_MEMORY_SCOPE_AGENT);
      v[2 * ks + 1] = __hip_atomic_load(hsrc + (size_t)ks * 128 + 1, __ATOMIC_RELAXED, __HIP_MEMORY_SCOPE_AGENT);
    }

    // acc init from xzf (VALU under load latency); even/odd-ks accumulator pairs
    f32x4 accA[4], accB[4];
#pragma unroll
    for (int gt = 0; gt < 4; ++gt)
#pragma unroll
      for (int q = 0; q < 4; ++q) { accA[gt][q] = xzf[gt * 4 + q]; accB[gt][q] = 0.f; }

#pragma unroll
    for (int ks = 0; ks < 16; ++ks) {
      union { unsigned long long u[2]; bf16x8 b; } cv;
      cv.u[0] = v[2 * ks]; cv.u[1] = v[2 * ks + 1];
      if (ks & 1) {
#pragma unroll
        for (int gt = 0; gt < 4; ++gt)
          accB[gt] = __builtin_amdgcn_mfma_f32_16x16x32_bf16(
              cv.b, __builtin_bit_cast(bf16x8, Bs[gt][ks]), accB[gt], 0, 0, 0);
      } else {
#pragma unroll
        for (int gt = 0; gt < 4; ++gt)
          accA[gt] = __builtin_amdgcn_mfma_f32_16x16x32_bf16(
              cv.b, __builtin_bit_cast(bf16x8, Bs[gt][ks]), accA[gt], 0, 0, 0);
      }
    }

    // gates + state update + publish
    unsigned long long* hdst = hring + (size_t)(t % R) * SLOT_U64;
#pragma unroll
    for (int q = 0; q < 4; ++q) {
      float zi = accA[0][q] + accB[0][q];
      float zf = accA[1][q] + accB[1][q];
      float zg = accA[2][q] + accB[2][q];
      float zo = accA[3][q] + accB[3][q];
      float ig = sigmoid_f(zi);
      float fg = sigmoid_f(zf);
      float gg = tanh_f(zg);
      float og = sigmoid_f(zo);
      float cn = fg * c4[q] + ig * gg;
      c4[q] = cn;
      float hv = og * tanh_f(cn);
      unsigned int my = f2bf(hv);
      unsigned int p1 = __shfl_xor(my, 1);
      unsigned int pair = my | (p1 << 16);
      unsigned int hi2 = __shfl_xor(pair, 2);
      if ((l15 & 3) == 0) {
        unsigned long long vv = (unsigned long long)pair | ((unsigned long long)hi2 << 32);
        __hip_atomic_store(&hdst[pbase + (size_t)(l4 * 4 + q) * 2], vv,
                           __ATOMIC_RELAXED, __HIP_MEMORY_SCOPE_AGENT);
      }
    }
    asm volatile("s_waitcnt vmcnt(0)" ::: "memory");   // drain store acks
    if (lane == 0)
      __hip_atomic_store(myflag, (unsigned int)(t + 1),
                         __ATOMIC_RELAXED, __HIP_MEMORY_SCOPE_AGENT);

    // convert prefetched xz for next iteration (loads long completed)
    if (t + 1 < tend) {
#pragma unroll
      for (int k = 0; k < 16; ++k) xzf[k] = __uint_as_float(raw[k] << 16);
    }
  }

  // save c for next chunk
#pragma unroll
  for (int q = 0; q < 4; ++q) cbuf[(bglob0 + l4 * 4 + q) * H_ + jcol] = c4[q];
}

extern "C" void kernel_launch(void* const* d_in, const int* in_sizes, int n_in,
                              void* d_out, int out_size, void* d_ws, size_t ws_size,
                              hipStream_t stream) {
  const int* seq    = (const int*)d_in[0];
  const float* emb  = (const float*)d_in[1];
  const float* Wx   = (const float*)d_in[2];
  const float* Wh   = (const float*)d_in[3];
  const float* bias = (const float*)d_in[4];
  float* out = (float*)d_out;
  char* ws = (char*)d_ws;

  unsigned short* embb = (unsigned short*)(ws + OFF_EMB);
  unsigned short* wxt  = (unsigned short*)(ws + OFF_WXT);
  unsigned short* wht  = (unsigned short*)(ws + OFF_WHT);
  float* cbuf          = (float*)(ws + OFF_C);
  unsigned int* flags  = (unsigned int*)(ws + OFF_FLAG);
  unsigned short* xz   = (unsigned short*)(ws + OFF_XZ);

  // chunk size: xz (TC slots) + h-ring (TC+1 slots) must fit after OFF_XZ
  size_t cap = (ws_size > OFF_XZ) ? (ws_size - OFF_XZ) : 0;
  int TC = (cap > RING_PER_T) ? (int)((cap - RING_PER_T) / (XZ_PER_T + RING_PER_T)) : 2;
  if (TC > T_) TC = T_;
  TC &= ~1;
  if (TC < 2) TC = 2;   // requires ws_size >= ~20.4 MB
  int R = TC + 1;
  unsigned long long* hring = (unsigned long long*)(ws + OFF_XZ + (size_t)TC * XZ_PER_T);

  hipMemsetAsync(flags, 0, 512, stream);   // monotone flags reset each launch/replay
  k_prep_emb<<<dim3(8000), dim3(256), 0, stream>>>(emb, embb);
  k_prep_w<<<dim3(6144), dim3(256), 0, stream>>>(Wx, Wh, wxt, wht);
  k_mask<<<dim3(128), dim3(256), 0, stream>>>(seq, out);

  for (int t0 = 0; t0 < T_; t0 += TC) {
    int tc = T_ - t0; if (tc > TC) tc = TC;
    k_gemm_xz<<<dim3((tc / 2) * 16), dim3(256), 0, stream>>>(seq, embb, wxt, bias, xz, t0);
    k_lstm<<<dim3(64), dim3(128), 0, stream>>>(wht, xz, (unsigned long long*)hring, cbuf,
                                               flags, t0, t0 + tc, R);
    k_copyseq<<<dim3(tc), dim3(256), 0, stream>>>((const unsigned int*)hring, out, t0, R);
  }
  k_hlast<<<dim3(128), dim3(256), 0, stream>>>((const unsigned int*)hring, out, R);
}

// Round 9
// 1586.936 us; speedup vs baseline: 1.7049x; 1.7049x over previous
//
#include <hip/hip_runtime.h>
#include <stdint.h>

// Problem constants
#define B_   64
#define T_   512
#define E_   256
#define H_   512
#define G4_  2048   // 4*H
#define V_   32000

// Output layout in d_out (floats): seq [64][512][512], h_last [64][512], mask [64][512]
#define OUT_SEQ   0
#define OUT_HLAST 16777216
#define OUT_MASK  16809984

// ws layout (bytes)
#define OFF_EMB  0u            // emb bf16 [32000][256]  = 16,384,000
#define OFF_WXT  16384000u     // WxT bf16 [2048][256]   =  1,048,576
#define OFF_WHT  17432576u     // WhT bf16 [2048][512]   =  2,097,152
#define OFF_C    19529728u     // cbuf f32  [64][512]    =    131,072
#define OFF_XZ   19660800u     // xz bf16 [TC][64][2048] = TC*262,144, then h-ring
#define XZ_PER_T   262144u
#define RING_PER_T  65536u     // one h slot: 4 groups x 64 kc x 16 b x 8 cols bf16
#define SLOT_U64    8192       // 65536 / 8

// h-slot layout (u64 units): idx = ((g*64 + kc)*16 + b)*2 + half
//   g = batch group (b/16), kc = j/8, b = batch within group, half = (j/4)&1.
// Consumer wave (lane l15=row, l4=k-quarter) reads, per ks, the u64 PAIR at
//   (g*64 + ks*4 + l4)*32 + l15*2  -> 16B aligned per lane, 1KB contiguous
// per instruction -> ONE global_load_dwordx4 per ks.

#define POISON64 0xFFFFFFFFFFFFFFFFULL

typedef short bf16x8 __attribute__((ext_vector_type(8)));
typedef float f32x4  __attribute__((ext_vector_type(4)));
typedef unsigned int u32x4 __attribute__((ext_vector_type(4)));

__device__ __forceinline__ unsigned short f2bf(float f) {
  uint32_t u = __float_as_uint(f);
  u = (u + 0x7FFFu + ((u >> 16) & 1u)) >> 16;   // RNE
  return (unsigned short)u;
}
__device__ __forceinline__ float bf2f(unsigned short h) {
  return __uint_as_float(((uint32_t)h) << 16);
}
// inf-safe fast gates
__device__ __forceinline__ float sigmoid_f(float x) {
  return __fdividef(1.f, 1.f + __expf(-x));
}
__device__ __forceinline__ float tanh_f(float x) {
  return 1.f - __fdividef(2.f, 1.f + __expf(2.f * x));
}

// ---------- prep: cast embedding table to bf16 ----------
__global__ void k_prep_emb(const float* __restrict__ emb, unsigned short* __restrict__ out) {
  int i = (blockIdx.x * 256 + threadIdx.x) * 4;   // 8,192,000 elems total
  if (i < V_ * E_) {
    float4 v = *(const float4*)(emb + i);
    ushort4 o;
    o.x = f2bf(v.x); o.y = f2bf(v.y); o.z = f2bf(v.z); o.w = f2bf(v.w);
    *(ushort4*)(out + i) = o;
  }
}

// ---------- prep: WxT, WhT (transposed bf16 copies) ----------
__global__ void k_prep_w(const float* __restrict__ Wx, const float* __restrict__ Wh,
                         unsigned short* __restrict__ wxt, unsigned short* __restrict__ wht) {
  int i = blockIdx.x * 256 + threadIdx.x;
  if (i < 524288) {                       // WxT[n][k] = Wx[k][n]
    int n = i >> 8, k = i & 255;
    wxt[i] = f2bf(Wx[k * G4_ + n]);
  } else if (i < 524288 + 1048576) {      // WhT[n][k] = Wh[k][n]
    int j = i - 524288;
    int n = j >> 9, k = j & 511;
    wht[j] = f2bf(Wh[k * G4_ + n]);
  }
}

// ---------- mask output ----------
__global__ void k_mask(const int* __restrict__ seq, float* __restrict__ out) {
  int i = blockIdx.x * 256 + threadIdx.x;       // 32768
  if (i < B_ * T_) out[OUT_MASK + i] = (seq[i] != 0) ? 1.f : 0.f;
}

// ---------- outseq: ring slot [g][kc][b][8] bf16 -> out [b][t][j] f32 ----------
__global__ __launch_bounds__(256) void k_copyseq(const unsigned int* __restrict__ ring,
                                                 float* __restrict__ out, int t0, int R) {
  int t = t0 + blockIdx.x;
  const unsigned int* src = ring + (size_t)(t % R) * (SLOT_U64 * 2);
  for (int i = threadIdx.x; i < B_ * H_ / 2; i += 256) {
    int b = i >> 8;
    int j = (i & 255) * 2;
    unsigned int v = src[((((b >> 4) * 64 + (j >> 3)) * 16 + (b & 15)) * 4) + ((j >> 1) & 3)];
    float2 o;
    o.x = bf2f((unsigned short)(v & 0xFFFFu));
    o.y = bf2f((unsigned short)(v >> 16));
    *(float2*)(out + ((size_t)b * T_ + t) * H_ + j) = o;
  }
}

// ---------- h_last from ring slot (T-1)%R ----------
__global__ void k_hlast(const unsigned int* __restrict__ ring, float* __restrict__ out, int R) {
  int i = blockIdx.x * 256 + threadIdx.x;       // 32768
  if (i < B_ * H_) {
    int b = i >> 9, j = i & 511;
    unsigned int v = ring[(size_t)((T_ - 1) % R) * (SLOT_U64 * 2) +
                          ((((b >> 4) * 64 + (j >> 3)) * 16 + (b & 15)) * 4) + ((j >> 1) & 3)];
    out[OUT_HLAST + i] = bf2f((unsigned short)((j & 1) ? (v >> 16) : (v & 0xFFFFu)));
  }
}

// ---------- phase 1: xz[m][n] = emb[seq][.]@Wx + b, m = (t-t0)*64 + b, bf16 out ----------
#define LDA_ 264
__global__ __launch_bounds__(256) void k_gemm_xz(
    const int* __restrict__ seq, const unsigned short* __restrict__ embb,
    const unsigned short* __restrict__ wxt, const float* __restrict__ bias,
    unsigned short* __restrict__ xz, int t0) {
  __shared__ __align__(16) unsigned short a_lds[128 * LDA_];
  __shared__ __align__(16) unsigned short b_lds[128 * LDA_];
  int bx = blockIdx.x & 15;     // N tile
  int by = blockIdx.x >> 4;     // M tile (chunk-local)
  int tid = threadIdx.x;

  { // stage A (gathered embedding rows) and B (WxT rows): 2 threads per 512B row
    int r = tid >> 1, half = tid & 1;
    int m = by * 128 + r;
    int t = t0 + (m >> 6), b = m & 63;
    int idx = seq[b * T_ + t];
    const unsigned short* srcA = embb + (size_t)idx * E_ + half * 128;
    const unsigned short* srcB = wxt + (size_t)(bx * 128 + r) * E_ + half * 128;
    unsigned short* dstA = a_lds + r * LDA_ + half * 128;
    unsigned short* dstB = b_lds + r * LDA_ + half * 128;
#pragma unroll
    for (int q = 0; q < 16; ++q) {
      *(bf16x8*)(dstA + q * 8) = *(const bf16x8*)(srcA + q * 8);
      *(bf16x8*)(dstB + q * 8) = *(const bf16x8*)(srcB + q * 8);
    }
  }
  __syncthreads();

  int w = tid >> 6, lane = tid & 63;
  int l15 = lane & 15, l4 = lane >> 4;
  int wm = w >> 1, wn = w & 1;
  f32x4 acc[4][4] = {};
#pragma unroll
  for (int ks = 0; ks < 8; ++ks) {
    bf16x8 a[4], bb[4];
#pragma unroll
    for (int mf = 0; mf < 4; ++mf)
      a[mf] = *(const bf16x8*)(a_lds + (wm * 64 + mf * 16 + l15) * LDA_ + ks * 32 + 8 * l4);
#pragma unroll
    for (int nf = 0; nf < 4; ++nf)
      bb[nf] = *(const bf16x8*)(b_lds + (wn * 64 + nf * 16 + l15) * LDA_ + ks * 32 + 8 * l4);
#pragma unroll
    for (int mf = 0; mf < 4; ++mf)
#pragma unroll
      for (int nf = 0; nf < 4; ++nf)
        acc[mf][nf] = __builtin_amdgcn_mfma_f32_16x16x32_bf16(a[mf], bb[nf], acc[mf][nf], 0, 0, 0);
  }
#pragma unroll
  for (int nf = 0; nf < 4; ++nf) {
    int n = bx * 128 + wn * 64 + nf * 16 + l15;
    float bv = bias[n];
#pragma unroll
    for (int mf = 0; mf < 4; ++mf)
#pragma unroll
      for (int q = 0; q < 4; ++q) {
        int m = by * 128 + wm * 64 + mf * 16 + l4 * 4 + q;
        xz[(size_t)m * G4_ + n] = f2bf(acc[mf][nf][q] + bv);
      }
  }
}

// ---------- phase 2: persistent LSTM recurrence (R5 structure, asm poll) ----------
// 64 WGs x 128 thr (2 waves): group g = bid&3 (16 batches), WG owns j-slice
// [32*(bid>>2), +32); wave w covers 16 j-cols x 4 gates; Wh frags pinned in
// registers via identity asm. h exchange: depth-R ring, [g][kc][b] layout,
// poison-validated fire-and-forget relaxed u64 stores (R5 protocol).
// Poll round = 16 x global_load_dwordx4 sc0 sc1 + ONE s_waitcnt vmcnt(0)
// (hand-written asm -> exactly one MALL round trip per poll round).
__global__ __launch_bounds__(128, 1) void k_lstm(
    const unsigned short* __restrict__ wht, const unsigned short* __restrict__ xz,
    unsigned long long* hring, float* cbuf, int t0, int tend, int R) {
  int bid = blockIdx.x;
  int g = bid & 3, nwg = bid >> 2;        // nwg in 0..15
  int J0 = nwg * 32;
  int tid = threadIdx.x;
  int w = tid >> 6, lane = tid & 63;
  int l15 = lane & 15, l4 = lane >> 4;
  int bglob0 = g * 16;
  int jcol = J0 + w * 16 + l15;          // this lane's j column (per gate)

  // B fragments in registers, pinned: Bs[gt][ks] = WhT[gt*512+jcol][ks*32+l4*8..+7]
  u32x4 Bs[4][16];
#pragma unroll
  for (int gt = 0; gt < 4; ++gt)
#pragma unroll
    for (int ks = 0; ks < 16; ++ks) {
      Bs[gt][ks] = *(const u32x4*)(wht + (size_t)(gt * 512 + jcol) * H_ + ks * 32 + l4 * 8);
      asm volatile("" : "+v"(Bs[gt][ks]));
    }

  float c4[4];
  if (t0 == 0) {
    c4[0] = c4[1] = c4[2] = c4[3] = 0.f;
  } else {
#pragma unroll
    for (int q = 0; q < 4; ++q) c4[q] = cbuf[(bglob0 + l4 * 4 + q) * H_ + jcol];
  }

  // producer store slot-cell base (u64): ((g*64 + jcol/8)*16)*2 + (jcol/4)&1, + b*2 per q
  size_t pbase = ((size_t)(g * 64 + (jcol >> 3)) * 16) * 2 + ((jcol >> 2) & 1);
  // consumer read base (BYTES): ((g*64 + l4)*32 + l15*2)*8; per-ks stride 1024B
  size_t rbyte = ((size_t)(g * 64 + l4) * 32 + l15 * 2) * 8;

  int xoff[16];
#pragma unroll
  for (int gt = 0; gt < 4; ++gt)
#pragma unroll
    for (int q = 0; q < 4; ++q)
      xoff[gt * 4 + q] = (l4 * 4 + q) * G4_ + gt * 512 + jcol;

  // xzf holds this step's input projections as f32
  float xzf[16];
  {
    const unsigned short* x0 = xz + (size_t)bglob0 * G4_;   // chunk-local t index 0
#pragma unroll
    for (int k = 0; k < 16; ++k) xzf[k] = bf2f(x0[xoff[k]]);
  }

  int t = t0;
  if (t0 == 0) {
    // step 0: h = gates(xz), c from zero
    unsigned long long* hdst = hring;           // slot 0
#pragma unroll
    for (int q = 0; q < 4; ++q) {
      float ig = sigmoid_f(xzf[0 * 4 + q]);
      float gg = tanh_f(xzf[2 * 4 + q]);
      float og = sigmoid_f(xzf[3 * 4 + q]);
      float cn = ig * gg;                       // f*c0 = 0
      c4[q] = cn;
      float hv = og * tanh_f(cn);
      unsigned int my = f2bf(hv);
      unsigned int p1 = __shfl_xor(my, 1);
      unsigned int pair = my | (p1 << 16);
      unsigned int hi2 = __shfl_xor(pair, 2);
      if ((l15 & 3) == 0) {
        unsigned long long vv = (unsigned long long)pair | ((unsigned long long)hi2 << 32);
        __hip_atomic_store(&hdst[pbase + (size_t)(l4 * 4 + q) * 2], vv,
                           __ATOMIC_RELAXED, __HIP_MEMORY_SCOPE_AGENT);
      }
    }
    t = 1;
    if (t < tend) {
      const unsigned short* x1 = xz + ((size_t)1 * B_ + bglob0) * G4_;
#pragma unroll
      for (int k = 0; k < 16; ++k) xzf[k] = bf2f(x1[xoff[k]]);
    }
  }

  for (; t < tend; ++t) {
    // acc init from xzf; even/odd-ks accumulator pairs (8 MFMA streams)
    f32x4 accA[4], accB[4];
#pragma unroll
    for (int gt = 0; gt < 4; ++gt)
#pragma unroll
      for (int q = 0; q < 4; ++q) { accA[gt][q] = xzf[gt * 4 + q]; accB[gt][q] = 0.f; }

    // prefetch next step's xz (issued before the poll; drained by poll's vmcnt)
    unsigned int raw[16];
    const unsigned short* xn = xz + ((size_t)(t + 1 - t0) * B_ + bglob0) * G4_;
    if (t + 1 < tend) {
#pragma unroll
      for (int k = 0; k < 16; ++k) raw[k] = xn[xoff[k]];
    }
    __builtin_amdgcn_sched_barrier(0);   // keep prefetch issue above the poll

    // poll h_{t-1}: 16 coalesced dwordx4 MALL loads, ONE waitcnt per round
    const char* hb = (const char*)hring + ((size_t)((t - 1) % R) * SLOT_U64) * 8 + rbyte;
    u32x4 v4[16];
    while (true) {
#pragma unroll
      for (int ks = 0; ks < 16; ++ks)
        asm volatile("global_load_dwordx4 %0, %1, off sc0 sc1"
                     : "=v"(v4[ks]) : "v"(hb + (size_t)ks * 1024));
      asm volatile("s_waitcnt vmcnt(0)" ::: "memory");
      __builtin_amdgcn_sched_barrier(0);   // rule #18: no hoisting past the waitcnt
      bool ok = true;
#pragma unroll
      for (int ks = 0; ks < 16; ++ks)
        ok &= (v4[ks][0] != 0xFFFFFFFFu) & (v4[ks][2] != 0xFFFFFFFFu);  // u64 stores are atomic: 1 dword check each
      if (__all(ok)) break;
      __builtin_amdgcn_s_sleep(1);
    }
    __builtin_amdgcn_sched_barrier(0);
    asm volatile("" ::: "memory");

#pragma unroll
    for (int ks = 0; ks < 16; ++ks) {
      bf16x8 a = __builtin_bit_cast(bf16x8, v4[ks]);
      if (ks & 1) {
#pragma unroll
        for (int gt = 0; gt < 4; ++gt)
          accB[gt] = __builtin_amdgcn_mfma_f32_16x16x32_bf16(
              a, __builtin_bit_cast(bf16x8, Bs[gt][ks]), accB[gt], 0, 0, 0);
      } else {
#pragma unroll
        for (int gt = 0; gt < 4; ++gt)
          accA[gt] = __builtin_amdgcn_mfma_f32_16x16x32_bf16(
              a, __builtin_bit_cast(bf16x8, Bs[gt][ks]), accA[gt], 0, 0, 0);
      }
    }

    // gates + state update + publish (fire-and-forget)
    unsigned long long* hdst = hring + (size_t)(t % R) * SLOT_U64;
#pragma unroll
    for (int q = 0; q < 4; ++q) {
      float zi = accA[0][q] + accB[0][q];
      float zf = accA[1][q] + accB[1][q];
      float zg = accA[2][q] + accB[2][q];
      float zo = accA[3][q] + accB[3][q];
      float ig = sigmoid_f(zi);
      float fg = sigmoid_f(zf);
      float gg = tanh_f(zg);
      float og = sigmoid_f(zo);
      float cn = fg * c4[q] + ig * gg;
      c4[q] = cn;
      float hv = og * tanh_f(cn);
      unsigned int my = f2bf(hv);
      unsigned int p1 = __shfl_xor(my, 1);
      unsigned int pair = my | (p1 << 16);
      unsigned int hi2 = __shfl_xor(pair, 2);
      if ((l15 & 3) == 0) {
        unsigned long long vv = (unsigned long long)pair | ((unsigned long long)hi2 << 32);
        __hip_atomic_store(&hdst[pbase + (size_t)(l4 * 4 + q) * 2], vv,
                           __ATOMIC_RELAXED, __HIP_MEMORY_SCOPE_AGENT);
      }
    }

    // convert prefetched xz for next iteration (loads completed by poll's vmcnt)
    if (t + 1 < tend) {
#pragma unroll
      for (int k = 0; k < 16; ++k) xzf[k] = __uint_as_float(raw[k] << 16);
    }
  }

  // save c for next chunk
#pragma unroll
  for (int q = 0; q < 4; ++q) cbuf[(bglob0 + l4 * 4 + q) * H_ + jcol] = c4[q];
}

extern "C" void kernel_launch(void* const* d_in, const int* in_sizes, int n_in,
                              void* d_out, int out_size, void* d_ws, size_t ws_size,
                              hipStream_t stream) {
  const int* seq    = (const int*)d_in[0];
  const float* emb  = (const float*)d_in[1];
  const float* Wx   = (const float*)d_in[2];
  const float* Wh   = (const float*)d_in[3];
  const float* bias = (const float*)d_in[4];
  float* out = (float*)d_out;
  char* ws = (char*)d_ws;

  unsigned short* embb = (unsigned short*)(ws + OFF_EMB);
  unsigned short* wxt  = (unsigned short*)(ws + OFF_WXT);
  unsigned short* wht  = (unsigned short*)(ws + OFF_WHT);
  float* cbuf          = (float*)(ws + OFF_C);
  unsigned short* xz   = (unsigned short*)(ws + OFF_XZ);

  // chunk size: xz (TC slots) + h-ring (TC+1 slots) must fit after OFF_XZ
  size_t cap = (ws_size > OFF_XZ) ? (ws_size - OFF_XZ) : 0;
  int TC = (cap > RING_PER_T) ? (int)((cap - RING_PER_T) / (XZ_PER_T + RING_PER_T)) : 2;
  if (TC > T_) TC = T_;
  TC &= ~1;
  if (TC < 2) TC = 2;   // requires ws_size >= ~20.4 MB
  int R = TC + 1;
  unsigned long long* hring = (unsigned long long*)(ws + OFF_XZ + (size_t)TC * XZ_PER_T);

  k_prep_emb<<<dim3(8000), dim3(256), 0, stream>>>(emb, embb);
  k_prep_w<<<dim3(6144), dim3(256), 0, stream>>>(Wx, Wh, wxt, wht);
  k_mask<<<dim3(128), dim3(256), 0, stream>>>(seq, out);

  for (int t0 = 0; t0 < T_; t0 += TC) {
    int tc = T_ - t0; if (tc > TC) tc = TC;
    // poison the tc ring slots this chunk will write: [t0 % R, +tc) mod R.
    int s0 = t0 % R;
    if (s0 + tc <= R) {
      hipMemsetAsync((char*)hring + (size_t)s0 * RING_PER_T, 0xFF, (size_t)tc * RING_PER_T, stream);
    } else {
      hipMemsetAsync((char*)hring + (size_t)s0 * RING_PER_T, 0xFF, (size_t)(R - s0) * RING_PER_T, stream);
      hipMemsetAsync((char*)hring, 0xFF, (size_t)(s0 + tc - R) * RING_PER_T, stream);
    }
    k_gemm_xz<<<dim3((tc / 2) * 16), dim3(256), 0, stream>>>(seq, embb, wxt, bias, xz, t0);
    k_lstm<<<dim3(64), dim3(128), 0, stream>>>(wht, xz, (unsigned long long*)hring, cbuf, t0, t0 + tc, R);
    k_copyseq<<<dim3(tc), dim3(256), 0, stream>>>((const unsigned int*)hring, out, t0, R);
  }
  k_hlast<<<dim3(128), dim3(256), 0, stream>>>((const unsigned int*)hring, out, R);
}